// Round 2
// baseline (552.597 us; speedup 1.0000x reference)
//
#include <hip/hip_runtime.h>
#include <cstdint>
#include <cstddef>

#define N_NODES  50000
#define N_EDGES  800000
#define DIM      128
#define N_GRAPHS 64

__device__ __forceinline__ int clamp_node(int v) {
    return v < 0 ? 0 : (v >= N_NODES ? N_NODES - 1 : v);
}

// ---------------------------------------------------------------------------
// CSR build: histogram of dst, scan, placement.
// edge_index arrives as int32: src = ei[0..E), dst = ei[E..2E).
// ---------------------------------------------------------------------------
__global__ void k_hist(const int* __restrict__ ei, int* __restrict__ hist) {
    int e = blockIdx.x * 256 + threadIdx.x;
    if (e < N_EDGES) atomicAdd(&hist[clamp_node(ei[N_EDGES + e])], 1);
}

__global__ void k_blocksum(const int* __restrict__ hist, int* __restrict__ bsum) {
    __shared__ int s[256];
    int base = blockIdx.x * 512;
    int t = threadIdx.x;
    int v = 0;
    if (base + t < N_NODES)       v += hist[base + t];
    if (base + 256 + t < N_NODES) v += hist[base + 256 + t];
    s[t] = v;
    __syncthreads();
    for (int off = 128; off > 0; off >>= 1) {
        if (t < off) s[t] += s[t + off];
        __syncthreads();
    }
    if (t == 0) bsum[blockIdx.x] = s[0];
}

__global__ void k_scan_bsum(int* bsum, int nb) {
    if (threadIdx.x == 0 && blockIdx.x == 0) {
        int acc = 0;
        for (int i = 0; i < nb; ++i) { int v = bsum[i]; bsum[i] = acc; acc += v; }
    }
}

__global__ void k_scan_write(const int* __restrict__ hist, const int* __restrict__ boff,
                             int* __restrict__ rs) {
    __shared__ int s[512];
    int t = threadIdx.x;
    int i = blockIdx.x * 512 + t;
    int v = (i < N_NODES) ? hist[i] : 0;
    s[t] = v;
    __syncthreads();
    // Hillis-Steele inclusive scan over 512 elements
    for (int off = 1; off < 512; off <<= 1) {
        int y = (t >= off) ? s[t - off] : 0;
        __syncthreads();
        s[t] += y;
        __syncthreads();
    }
    int base = boff[blockIdx.x];
    if (i < N_NODES)     rs[i] = base + s[t] - v;   // exclusive scan = row start
    if (i == N_NODES - 1) rs[N_NODES] = base + s[t];
}

// After this kernel rs[d] holds END offset of node d. start(n) = rs[n-1].
__global__ void k_place(const int* __restrict__ ei, int* __restrict__ rs,
                        int* __restrict__ srcs) {
    int e = blockIdx.x * 256 + threadIdx.x;
    if (e < N_EDGES) {
        int d = clamp_node(ei[N_EDGES + e]);
        int pos = atomicAdd(&rs[d], 1);
        if (pos >= 0 && pos < N_EDGES) srcs[pos] = clamp_node(ei[e]);
    }
}

// ---------------------------------------------------------------------------
// Pull-style mean-aggregation (sum only; division fused into GEMM).
// One wave per node; lane owns 2 feature dims (float2) -> coalesced 512B rows.
// ---------------------------------------------------------------------------
__global__ __launch_bounds__(256) void k_agg(const float* __restrict__ feat,
                                             const int* __restrict__ rs,
                                             const int* __restrict__ srcs,
                                             float* __restrict__ agg) {
    int gtid = blockIdx.x * 256 + threadIdx.x;
    int wid  = gtid >> 6;
    int lane = threadIdx.x & 63;
    if (wid >= N_NODES) return;
    int start = (wid == 0) ? 0 : rs[wid - 1];
    int end   = rs[wid];
    float2 acc = make_float2(0.f, 0.f);
    int col = lane * 2;
    for (int e = start; e < end; ++e) {
        int sn = srcs[e];
        float2 v = *(const float2*)&feat[(size_t)sn * DIM + col];
        acc.x += v.x; acc.y += v.y;
    }
    *(float2*)&agg[(size_t)wid * DIM + col] = acc;
}

// ---------------------------------------------------------------------------
// Fused SAGE layer: out = relu( Wl @ (agg*invdeg) + bias + Wr @ in2 )
// K = 256 (concat). Block: 256 threads, 32 rows. 4 K-chunks of 64, weights
// transposed into LDS. Each thread: 4 rows x 4 outs f32 accumulator.
// out may alias aggin (each block reads only its own rows, staged to LDS
// before the final store).
// ---------------------------------------------------------------------------
__global__ __launch_bounds__(256) void k_gemm(const float* __restrict__ aggin,
                                              const int* __restrict__ rs,
                                              const float* __restrict__ in2,
                                              const float* __restrict__ Wl,
                                              const float* __restrict__ bias,
                                              const float* __restrict__ Wr,
                                              float* __restrict__ outp) {
    __shared__ float inT[32][256];   // 32 KB: [row][k] k<128: agg*invd, k>=128: in2
    __shared__ float Wt[64][132];    // 33.8 KB transposed weight chunk [k][o], padded
    __shared__ float invd[32];

    int row0 = blockIdx.x * 32;
    int t = threadIdx.x;

    if (t < 32) {
        int n = row0 + t;
        float dg = 0.f;
        if (n < N_NODES) {
            int s0 = (n == 0) ? 0 : rs[n - 1];
            dg = (float)(rs[n] - s0);
        }
        invd[t] = 1.0f / fmaxf(dg, 1.0f);
    }
    __syncthreads();

    // stage 32 rows x (128+128) floats, float4 granularity
    for (int idx = t; idx < 32 * 32; idx += 256) {
        int r  = idx >> 5;
        int k4 = (idx & 31) << 2;
        int n  = row0 + r;
        float4 a = make_float4(0, 0, 0, 0), b = make_float4(0, 0, 0, 0);
        if (n < N_NODES) {
            a = *(const float4*)&aggin[(size_t)n * DIM + k4];
            b = *(const float4*)&in2 [(size_t)n * DIM + k4];
        }
        float sc = invd[r];
        a.x *= sc; a.y *= sc; a.z *= sc; a.w *= sc;
        *(float4*)&inT[r][k4]       = a;
        *(float4*)&inT[r][128 + k4] = b;
    }

    float acc[4][4] = {};
    int oo = (t & 31) << 2;  // output cols oo..oo+3
    int rr = t >> 5;         // rows rr, rr+8, rr+16, rr+24

    for (int c = 0; c < 4; ++c) {
        const float* Wsrc = (c < 2) ? Wl : Wr;
        int kbase = (c & 1) << 6;
        // transpose-stage 64x128 weight chunk
        {
            int o  = t >> 1;
            int kk = (t & 1) << 5;
            const float* wp = Wsrc + o * DIM + kbase + kk;
            #pragma unroll
            for (int j = 0; j < 8; ++j) {
                float4 wv = *(const float4*)(wp + j * 4);
                Wt[kk + j * 4 + 0][o] = wv.x;
                Wt[kk + j * 4 + 1][o] = wv.y;
                Wt[kk + j * 4 + 2][o] = wv.z;
                Wt[kk + j * 4 + 3][o] = wv.w;
            }
        }
        __syncthreads();
        int kin = c << 6;
        #pragma unroll
        for (int k = 0; k < 64; k += 4) {
            float4 w0 = *(const float4*)&Wt[k + 0][oo];
            float4 w1 = *(const float4*)&Wt[k + 1][oo];
            float4 w2 = *(const float4*)&Wt[k + 2][oo];
            float4 w3 = *(const float4*)&Wt[k + 3][oo];
            #pragma unroll
            for (int m = 0; m < 4; ++m) {
                float4 a = *(const float4*)&inT[rr + (m << 3)][kin + k];
                acc[m][0] += a.x * w0.x; acc[m][1] += a.x * w0.y;
                acc[m][2] += a.x * w0.z; acc[m][3] += a.x * w0.w;
                acc[m][0] += a.y * w1.x; acc[m][1] += a.y * w1.y;
                acc[m][2] += a.y * w1.z; acc[m][3] += a.y * w1.w;
                acc[m][0] += a.z * w2.x; acc[m][1] += a.z * w2.y;
                acc[m][2] += a.z * w2.z; acc[m][3] += a.z * w2.w;
                acc[m][0] += a.w * w3.x; acc[m][1] += a.w * w3.y;
                acc[m][2] += a.w * w3.z; acc[m][3] += a.w * w3.w;
            }
        }
        __syncthreads();
    }

    float4 bb = *(const float4*)&bias[oo];
    #pragma unroll
    for (int m = 0; m < 4; ++m) {
        int n = row0 + rr + (m << 3);
        if (n < N_NODES) {
            float4 o4;
            o4.x = fmaxf(acc[m][0] + bb.x, 0.f);
            o4.y = fmaxf(acc[m][1] + bb.y, 0.f);
            o4.z = fmaxf(acc[m][2] + bb.z, 0.f);
            o4.w = fmaxf(acc[m][3] + bb.w, 0.f);
            *(float4*)&outp[(size_t)n * DIM + oo] = o4;
        }
    }
}

// ---------------------------------------------------------------------------
// Global mean pool (batch sorted -> binary search ranges) + fused MLP head.
// One block per graph. batch arrives as int32.
// ---------------------------------------------------------------------------
__global__ __launch_bounds__(256) void k_pool_head(const float* __restrict__ h2,
                                                   const int* __restrict__ batch,
                                                   const float* __restrict__ wl1,
                                                   const float* __restrict__ bl1,
                                                   const float* __restrict__ wout,
                                                   const float* __restrict__ bout,
                                                   float* __restrict__ out) {
    int g = blockIdx.x;
    int t = threadIdx.x;
    int lane = t & 63;
    int wv   = t >> 6;

    int lo = 0, hi = N_NODES;
    while (lo < hi) { int mid = (lo + hi) >> 1; if (batch[mid] < g) lo = mid + 1; else hi = mid; }
    int s = lo;
    lo = 0; hi = N_NODES;
    while (lo < hi) { int mid = (lo + hi) >> 1; if (batch[mid] < g + 1) lo = mid + 1; else hi = mid; }
    int e = lo;

    float2 acc = make_float2(0.f, 0.f);
    int col = lane * 2;
    for (int n = s + wv; n < e; n += 4) {
        float2 v = *(const float2*)&h2[(size_t)n * DIM + col];
        acc.x += v.x; acc.y += v.y;
    }
    __shared__ float red[4][DIM];
    __shared__ float gvec[DIM];
    red[wv][col] = acc.x; red[wv][col + 1] = acc.y;
    __syncthreads();
    if (t < DIM) {
        float sm = red[0][t] + red[1][t] + red[2][t] + red[3][t];
        float cnt = fmaxf((float)(e - s), 1.0f);
        gvec[t] = sm / cnt;
    }
    __syncthreads();
    if (t < 64) {
        float a = bl1[t];
        #pragma unroll 4
        for (int k = 0; k < DIM; ++k) a += wl1[t * DIM + k] * gvec[k];
        float g1 = fmaxf(a, 0.f) * wout[t];
        #pragma unroll
        for (int off = 32; off > 0; off >>= 1) g1 += __shfl_down(g1, off);
        if (t == 0) {
            float z = g1 + bout[0];
            out[g] = 1.0f / (1.0f + expf(-z));
        }
    }
}

// ---------------------------------------------------------------------------
extern "C" void kernel_launch(void* const* d_in, const int* in_sizes, int n_in,
                              void* d_out, int out_size, void* d_ws, size_t ws_size,
                              hipStream_t stream) {
    const float* x     = (const float*)d_in[0];
    const int*   ei    = (const int*)d_in[1];    // int64 in reference -> int32 here
    const int*   batch = (const int*)d_in[2];    // int64 in reference -> int32 here
    const float* w1l   = (const float*)d_in[3];
    const float* b1l   = (const float*)d_in[4];
    const float* w1r   = (const float*)d_in[5];
    const float* w2l   = (const float*)d_in[6];
    const float* b2l   = (const float*)d_in[7];
    const float* w2r   = (const float*)d_in[8];
    const float* wl1   = (const float*)d_in[9];
    const float* bl1   = (const float*)d_in[10];
    const float* wout  = (const float*)d_in[11];
    const float* bout  = (const float*)d_in[12];
    float* out = (float*)d_out;

    char*  wsp = (char*)d_ws;
    size_t off = 0;
    auto alloc = [&](size_t bytes) -> char* {
        char* p = wsp + off;
        off += (bytes + 255) & ~(size_t)255;
        return p;
    };
    int*   rs   = (int*)alloc((size_t)(N_NODES + 1) * 4);
    int*   hist = (int*)alloc((size_t)N_NODES * 4);
    int*   bsum = (int*)alloc(256 * 4);
    int*   srcs = (int*)alloc((size_t)N_EDGES * 4);
    float* agg  = (float*)alloc((size_t)N_NODES * DIM * 4);
    float* h1   = (float*)alloc((size_t)N_NODES * DIM * 4);

    const int nb = (N_NODES + 511) / 512;   // 98

    hipMemsetAsync(hist, 0, (size_t)N_NODES * 4, stream);
    k_hist<<<(N_EDGES + 255) / 256, 256, 0, stream>>>(ei, hist);
    k_blocksum<<<nb, 256, 0, stream>>>(hist, bsum);
    k_scan_bsum<<<1, 64, 0, stream>>>(bsum, nb);
    k_scan_write<<<nb, 512, 0, stream>>>(hist, bsum, rs);
    k_place<<<(N_EDGES + 255) / 256, 256, 0, stream>>>(ei, rs, srcs);

    // conv1
    k_agg<<<N_NODES / 4, 256, 0, stream>>>(x, rs, srcs, agg);
    k_gemm<<<(N_NODES + 31) / 32, 256, 0, stream>>>(agg, rs, x, w1l, b1l, w1r, h1);
    // conv2 (output aliases agg; safe: each block only touches its own rows)
    k_agg<<<N_NODES / 4, 256, 0, stream>>>(h1, rs, srcs, agg);
    k_gemm<<<(N_NODES + 31) / 32, 256, 0, stream>>>(agg, rs, h1, w2l, b2l, w2r, agg);
    // pool + head
    k_pool_head<<<N_GRAPHS, 256, 0, stream>>>(agg, batch, wl1, bl1, wout, bout, out);
}

// Round 3
// 380.793 us; speedup vs baseline: 1.4512x; 1.4512x over previous
//
#include <hip/hip_runtime.h>
#include <cstdint>
#include <cstddef>

#define N_NODES  50000
#define N_EDGES  800000
#define DIM      128
#define N_GRAPHS 64

typedef __attribute__((ext_vector_type(8))) short     bf16x8;
typedef __attribute__((ext_vector_type(4))) float     f32x4;

__device__ __forceinline__ int clamp_node(int v) {
    return v < 0 ? 0 : (v >= N_NODES ? N_NODES - 1 : v);
}
__device__ __forceinline__ unsigned short f2bf(float f) {
    union { float f; unsigned u; } v; v.f = f;
    unsigned r = v.u + 0x7FFF + ((v.u >> 16) & 1);   // round-to-nearest-even
    return (unsigned short)(r >> 16);
}
__device__ __forceinline__ float bflo(unsigned u) {
    union { unsigned u; float f; } v; v.u = u << 16; return v.f;
}
__device__ __forceinline__ float bfhi(unsigned u) {
    union { unsigned u; float f; } v; v.u = u & 0xFFFF0000u; return v.f;
}

// ---------------------------------------------------------------------------
// CSR build: histogram of dst, scan, placement. edge_index arrives as int32.
// ---------------------------------------------------------------------------
__global__ void k_hist(const int* __restrict__ ei, int* __restrict__ hist) {
    int e = blockIdx.x * 256 + threadIdx.x;
    if (e < N_EDGES) atomicAdd(&hist[clamp_node(ei[N_EDGES + e])], 1);
}

__global__ void k_blocksum(const int* __restrict__ hist, int* __restrict__ bsum) {
    __shared__ int s[256];
    int base = blockIdx.x * 512;
    int t = threadIdx.x;
    int v = 0;
    if (base + t < N_NODES)       v += hist[base + t];
    if (base + 256 + t < N_NODES) v += hist[base + 256 + t];
    s[t] = v;
    __syncthreads();
    for (int off = 128; off > 0; off >>= 1) {
        if (t < off) s[t] += s[t + off];
        __syncthreads();
    }
    if (t == 0) bsum[blockIdx.x] = s[0];
}

__global__ void k_scan_bsum(int* bsum, int nb) {
    if (threadIdx.x == 0 && blockIdx.x == 0) {
        int acc = 0;
        for (int i = 0; i < nb; ++i) { int v = bsum[i]; bsum[i] = acc; acc += v; }
    }
}

__global__ void k_scan_write(const int* __restrict__ hist, const int* __restrict__ boff,
                             int* __restrict__ rs) {
    __shared__ int s[512];
    int t = threadIdx.x;
    int i = blockIdx.x * 512 + t;
    int v = (i < N_NODES) ? hist[i] : 0;
    s[t] = v;
    __syncthreads();
    for (int off = 1; off < 512; off <<= 1) {
        int y = (t >= off) ? s[t - off] : 0;
        __syncthreads();
        s[t] += y;
        __syncthreads();
    }
    int base = boff[blockIdx.x];
    if (i < N_NODES)      rs[i] = base + s[t] - v;
    if (i == N_NODES - 1) rs[N_NODES] = base + s[t];
}

// After this kernel rs[d] holds END offset of node d. start(n) = rs[n-1].
__global__ void k_place(const int* __restrict__ ei, int* __restrict__ rs,
                        int* __restrict__ srcs) {
    int e = blockIdx.x * 256 + threadIdx.x;
    if (e < N_EDGES) {
        int d = clamp_node(ei[N_EDGES + e]);
        int pos = atomicAdd(&rs[d], 1);
        if (pos >= 0 && pos < N_EDGES) srcs[pos] = clamp_node(ei[e]);
    }
}

// ---------------------------------------------------------------------------
// f32 -> bf16 bulk convert (8 elems/thread).
// ---------------------------------------------------------------------------
__global__ __launch_bounds__(256) void k_tobf16(const float* __restrict__ in,
                                                unsigned short* __restrict__ outp,
                                                int n8) {
    int i = blockIdx.x * 256 + threadIdx.x;
    if (i >= n8) return;
    const float4* p = (const float4*)(in + (size_t)i * 8);
    float4 a = p[0], b = p[1];
    union { unsigned short s[8]; uint4 u; } o;
    o.s[0] = f2bf(a.x); o.s[1] = f2bf(a.y); o.s[2] = f2bf(a.z); o.s[3] = f2bf(a.w);
    o.s[4] = f2bf(b.x); o.s[5] = f2bf(b.y); o.s[6] = f2bf(b.z); o.s[7] = f2bf(b.w);
    *(uint4*)(outp + (size_t)i * 8) = o.u;
}

// ---------------------------------------------------------------------------
// Pack concat weight [Wl;Wr]^T (B operand, [k=256][o=128]) into MFMA fragment
// order: frag[(ot*8+ks)*64 + lane][j] = B[ks*32 + (lane>>4)*8 + j][ot*16 + (lane&15)]
// 4096 threads, 8 bf16 (16B) each.
// ---------------------------------------------------------------------------
__global__ void k_wprep(const float* __restrict__ Wl, const float* __restrict__ Wr,
                        unsigned short* __restrict__ wbuf) {
    int tid = blockIdx.x * 256 + threadIdx.x;
    if (tid >= 8 * 8 * 64) return;
    int lane = tid & 63;
    int ks   = (tid >> 6) & 7;
    int ot   = tid >> 9;
    int o  = ot * 16 + (lane & 15);
    int kb = ks * 32 + ((lane >> 4) << 3);
    union { unsigned short s[8]; uint4 u; } frag;
    #pragma unroll
    for (int j = 0; j < 8; ++j) {
        int k = kb + j;
        float v = (k < DIM) ? Wl[o * DIM + k] : Wr[o * DIM + (k - DIM)];
        frag.s[j] = f2bf(v);
    }
    *(uint4*)(wbuf + (size_t)tid * 8) = frag.u;
}

// ---------------------------------------------------------------------------
// Pull-style mean-aggregation over bf16 feature rows. One wave per node,
// lane owns cols 2*lane, 2*lane+1 (4B/lane -> 256B coalesced row reads).
// Stores mean directly in bf16 (invdeg folded in).
// ---------------------------------------------------------------------------
__global__ __launch_bounds__(256) void k_agg(const unsigned short* __restrict__ feat,
                                             const int* __restrict__ rs,
                                             const int* __restrict__ srcs,
                                             unsigned short* __restrict__ agg) {
    int gtid = blockIdx.x * 256 + threadIdx.x;
    int wid  = gtid >> 6;
    int lane = threadIdx.x & 63;
    if (wid >= N_NODES) return;
    int start = (wid == 0) ? 0 : rs[wid - 1];
    int end   = rs[wid];
    float ax = 0.f, ay = 0.f;
    for (int e = start; e < end; ++e) {
        int sn = srcs[e];
        unsigned u = *(const unsigned*)(feat + (size_t)sn * DIM + 2 * lane);
        ax += bflo(u); ay += bfhi(u);
    }
    float inv = 1.0f / fmaxf((float)(end - start), 1.0f);
    unsigned pk = (unsigned)f2bf(ax * inv) | ((unsigned)f2bf(ay * inv) << 16);
    *(unsigned*)(agg + (size_t)wid * DIM + 2 * lane) = pk;
}

// ---------------------------------------------------------------------------
// Fused SAGE layer via MFMA: out = relu( [aggmean ; in2] @ Wcat + bias ), bf16.
// Block = 4 waves; wave w computes 16 nodes x 32 outs (out tiles 2w, 2w+1).
// No LDS: A-fragments straight from global in fragment layout; B-fragments
// preloaded from wbuf (64 VGPR, resident). K = 256 -> 8 MFMA k-steps.
// ---------------------------------------------------------------------------
__global__ __launch_bounds__(256) void k_mm(const unsigned short* __restrict__ aggb,
                                            const unsigned short* __restrict__ in2b,
                                            const unsigned short* __restrict__ wbuf,
                                            const float* __restrict__ bias,
                                            unsigned short* __restrict__ outb) {
    int t    = threadIdx.x;
    int wave = t >> 6;
    int lane = t & 63;
    int n0   = blockIdx.x * 16;
    int row  = lane & 15;
    int kl   = (lane >> 4) << 3;

    // B fragments: 2 out-tiles x 8 k-steps, 16B/lane coalesced
    bf16x8 B[2][8];
    #pragma unroll
    for (int ot = 0; ot < 2; ++ot)
        #pragma unroll
        for (int ks = 0; ks < 8; ++ks)
            B[ot][ks] = *(const bf16x8*)(wbuf +
                (((size_t)(wave * 2 + ot) * 8 + ks) * 64 + lane) * 8);

    // A fragments: k<128 from aggmean, k>=128 from in2
    bf16x8 A[8];
    const unsigned short* arow = aggb + (size_t)(n0 + row) * DIM + kl;
    const unsigned short* xrow = in2b + (size_t)(n0 + row) * DIM + kl;
    #pragma unroll
    for (int ks = 0; ks < 4; ++ks) A[ks]     = *(const bf16x8*)(arow + ks * 32);
    #pragma unroll
    for (int ks = 0; ks < 4; ++ks) A[4 + ks] = *(const bf16x8*)(xrow + ks * 32);

    f32x4 acc0 = {0.f, 0.f, 0.f, 0.f}, acc1 = {0.f, 0.f, 0.f, 0.f};
    #pragma unroll
    for (int ks = 0; ks < 8; ++ks) {
        acc0 = __builtin_amdgcn_mfma_f32_16x16x32_bf16(A[ks], B[0][ks], acc0, 0, 0, 0);
        acc1 = __builtin_amdgcn_mfma_f32_16x16x32_bf16(A[ks], B[1][ks], acc1, 0, 0, 0);
    }

    // C/D layout: col = lane&15, row = (lane>>4)*4 + reg   [m89-verified]
    int o0   = wave * 32;
    int ocol = lane & 15;
    int rb   = (lane >> 4) << 2;
    float b0 = bias[o0 + ocol];
    float b1 = bias[o0 + 16 + ocol];
    #pragma unroll
    for (int r = 0; r < 4; ++r) {
        size_t n = (size_t)(n0 + rb + r);
        outb[n * DIM + o0 + ocol]      = f2bf(fmaxf(acc0[r] + b0, 0.f));
        outb[n * DIM + o0 + 16 + ocol] = f2bf(fmaxf(acc1[r] + b1, 0.f));
    }
}

// ---------------------------------------------------------------------------
// Global mean pool (batch sorted -> binary search) + fused MLP head.
// One block per graph; h2 is bf16.
// ---------------------------------------------------------------------------
__global__ __launch_bounds__(256) void k_pool_head(const unsigned short* __restrict__ h2,
                                                   const int* __restrict__ batch,
                                                   const float* __restrict__ wl1,
                                                   const float* __restrict__ bl1,
                                                   const float* __restrict__ wout,
                                                   const float* __restrict__ bout,
                                                   float* __restrict__ out) {
    int g = blockIdx.x;
    int t = threadIdx.x;
    int lane = t & 63;
    int wv   = t >> 6;

    int lo = 0, hi = N_NODES;
    while (lo < hi) { int mid = (lo + hi) >> 1; if (batch[mid] < g) lo = mid + 1; else hi = mid; }
    int s = lo;
    lo = 0; hi = N_NODES;
    while (lo < hi) { int mid = (lo + hi) >> 1; if (batch[mid] < g + 1) lo = mid + 1; else hi = mid; }
    int e = lo;

    float ax = 0.f, ay = 0.f;
    for (int n = s + wv; n < e; n += 4) {
        unsigned u = *(const unsigned*)(h2 + (size_t)n * DIM + 2 * lane);
        ax += bflo(u); ay += bfhi(u);
    }
    __shared__ float red[4][DIM];
    __shared__ float gvec[DIM];
    red[wv][2 * lane] = ax; red[wv][2 * lane + 1] = ay;
    __syncthreads();
    if (t < DIM) {
        float sm = red[0][t] + red[1][t] + red[2][t] + red[3][t];
        float cnt = fmaxf((float)(e - s), 1.0f);
        gvec[t] = sm / cnt;
    }
    __syncthreads();
    if (t < 64) {
        float a = bl1[t];
        #pragma unroll 4
        for (int k = 0; k < DIM; ++k) a += wl1[t * DIM + k] * gvec[k];
        float g1 = fmaxf(a, 0.f) * wout[t];
        #pragma unroll
        for (int off = 32; off > 0; off >>= 1) g1 += __shfl_down(g1, off);
        if (t == 0) {
            float z = g1 + bout[0];
            out[g] = 1.0f / (1.0f + expf(-z));
        }
    }
}

// ---------------------------------------------------------------------------
extern "C" void kernel_launch(void* const* d_in, const int* in_sizes, int n_in,
                              void* d_out, int out_size, void* d_ws, size_t ws_size,
                              hipStream_t stream) {
    const float* x     = (const float*)d_in[0];
    const int*   ei    = (const int*)d_in[1];    // int64 in ref -> int32 here
    const int*   batch = (const int*)d_in[2];
    const float* w1l   = (const float*)d_in[3];
    const float* b1l   = (const float*)d_in[4];
    const float* w1r   = (const float*)d_in[5];
    const float* w2l   = (const float*)d_in[6];
    const float* b2l   = (const float*)d_in[7];
    const float* w2r   = (const float*)d_in[8];
    const float* wl1   = (const float*)d_in[9];
    const float* bl1   = (const float*)d_in[10];
    const float* wout  = (const float*)d_in[11];
    const float* bout  = (const float*)d_in[12];
    float* out = (float*)d_out;

    char*  wsp = (char*)d_ws;
    size_t off = 0;
    auto alloc = [&](size_t bytes) -> char* {
        char* p = wsp + off;
        off += (bytes + 255) & ~(size_t)255;
        return p;
    };
    int* rs   = (int*)alloc((size_t)(N_NODES + 1) * 4);
    int* hist = (int*)alloc((size_t)N_NODES * 4);
    int* bsum = (int*)alloc(256 * 4);
    int* srcs = (int*)alloc((size_t)N_EDGES * 4);
    unsigned short* xb    = (unsigned short*)alloc((size_t)N_NODES * DIM * 2);
    unsigned short* aggb  = (unsigned short*)alloc((size_t)N_NODES * DIM * 2);
    unsigned short* h1b   = (unsigned short*)alloc((size_t)N_NODES * DIM * 2);
    unsigned short* h2b   = (unsigned short*)alloc((size_t)N_NODES * DIM * 2);
    unsigned short* wbuf1 = (unsigned short*)alloc((size_t)8 * 8 * 64 * 8 * 2);
    unsigned short* wbuf2 = (unsigned short*)alloc((size_t)8 * 8 * 64 * 8 * 2);

    const int nb = (N_NODES + 511) / 512;   // 98

    hipMemsetAsync(hist, 0, (size_t)N_NODES * 4, stream);
    k_hist<<<(N_EDGES + 255) / 256, 256, 0, stream>>>(ei, hist);
    k_blocksum<<<nb, 256, 0, stream>>>(hist, bsum);
    k_scan_bsum<<<1, 64, 0, stream>>>(bsum, nb);
    k_scan_write<<<nb, 512, 0, stream>>>(hist, bsum, rs);
    k_place<<<(N_EDGES + 255) / 256, 256, 0, stream>>>(ei, rs, srcs);

    // dtype prep
    k_tobf16<<<(N_NODES * DIM / 8 + 255) / 256, 256, 0, stream>>>(x, xb, N_NODES * DIM / 8);
    k_wprep<<<16, 256, 0, stream>>>(w1l, w1r, wbuf1);
    k_wprep<<<16, 256, 0, stream>>>(w2l, w2r, wbuf2);

    // conv1
    k_agg<<<N_NODES / 4, 256, 0, stream>>>(xb, rs, srcs, aggb);
    k_mm<<<N_NODES / 16, 256, 0, stream>>>(aggb, xb, wbuf1, b1l, h1b);
    // conv2
    k_agg<<<N_NODES / 4, 256, 0, stream>>>(h1b, rs, srcs, aggb);
    k_mm<<<N_NODES / 16, 256, 0, stream>>>(aggb, h1b, wbuf2, b2l, h2b);
    // pool + head
    k_pool_head<<<N_GRAPHS, 256, 0, stream>>>(h2b, batch, wl1, bl1, wout, bout, out);
}

// Round 4
// 286.833 us; speedup vs baseline: 1.9265x; 1.3276x over previous
//
#include <hip/hip_runtime.h>
#include <cstdint>
#include <cstddef>

#define N_NODES  50000
#define N_EDGES  800000
#define DIM      128
#define N_GRAPHS 64

typedef __attribute__((ext_vector_type(8))) short     bf16x8;
typedef __attribute__((ext_vector_type(4))) float     f32x4;

__device__ __forceinline__ int clamp_node(int v) {
    return v < 0 ? 0 : (v >= N_NODES ? N_NODES - 1 : v);
}
__device__ __forceinline__ unsigned short f2bf(float f) {
    union { float f; unsigned u; } v; v.f = f;
    unsigned r = v.u + 0x7FFF + ((v.u >> 16) & 1);   // round-to-nearest-even
    return (unsigned short)(r >> 16);
}
__device__ __forceinline__ float bflo(unsigned u) {
    union { unsigned u; float f; } v; v.u = u << 16; return v.f;
}
__device__ __forceinline__ float bfhi(unsigned u) {
    union { unsigned u; float f; } v; v.u = u & 0xFFFF0000u; return v.f;
}

// ---------------------------------------------------------------------------
// CSR build: histogram of dst, scan, placement. edge_index arrives as int32.
// ---------------------------------------------------------------------------
__global__ void k_hist(const int* __restrict__ ei, int* __restrict__ hist) {
    int e = blockIdx.x * 256 + threadIdx.x;
    if (e < N_EDGES) atomicAdd(&hist[clamp_node(ei[N_EDGES + e])], 1);
}

__global__ void k_blocksum(const int* __restrict__ hist, int* __restrict__ bsum) {
    __shared__ int s[256];
    int base = blockIdx.x * 512;
    int t = threadIdx.x;
    int v = 0;
    if (base + t < N_NODES)       v += hist[base + t];
    if (base + 256 + t < N_NODES) v += hist[base + 256 + t];
    s[t] = v;
    __syncthreads();
    for (int off = 128; off > 0; off >>= 1) {
        if (t < off) s[t] += s[t + off];
        __syncthreads();
    }
    if (t == 0) bsum[blockIdx.x] = s[0];
}

__global__ void k_scan_bsum(int* bsum, int nb) {
    if (threadIdx.x == 0 && blockIdx.x == 0) {
        int acc = 0;
        for (int i = 0; i < nb; ++i) { int v = bsum[i]; bsum[i] = acc; acc += v; }
    }
}

__global__ void k_scan_write(const int* __restrict__ hist, const int* __restrict__ boff,
                             int* __restrict__ rs) {
    __shared__ int s[512];
    int t = threadIdx.x;
    int i = blockIdx.x * 512 + t;
    int v = (i < N_NODES) ? hist[i] : 0;
    s[t] = v;
    __syncthreads();
    for (int off = 1; off < 512; off <<= 1) {
        int y = (t >= off) ? s[t - off] : 0;
        __syncthreads();
        s[t] += y;
        __syncthreads();
    }
    int base = boff[blockIdx.x];
    if (i < N_NODES)      rs[i] = base + s[t] - v;
    if (i == N_NODES - 1) rs[N_NODES] = base + s[t];
}

// After this kernel rs[d] holds END offset of node d. start(n) = rs[n-1].
__global__ void k_place(const int* __restrict__ ei, int* __restrict__ rs,
                        int* __restrict__ srcs) {
    int e = blockIdx.x * 256 + threadIdx.x;
    if (e < N_EDGES) {
        int d = clamp_node(ei[N_EDGES + e]);
        int pos = atomicAdd(&rs[d], 1);
        if (pos >= 0 && pos < N_EDGES) srcs[pos] = clamp_node(ei[e]);
    }
}

// ---------------------------------------------------------------------------
// f32 -> bf16 bulk convert (8 elems/thread).
// ---------------------------------------------------------------------------
__global__ __launch_bounds__(256) void k_tobf16(const float* __restrict__ in,
                                                unsigned short* __restrict__ outp,
                                                int n8) {
    int i = blockIdx.x * 256 + threadIdx.x;
    if (i >= n8) return;
    const float4* p = (const float4*)(in + (size_t)i * 8);
    float4 a = p[0], b = p[1];
    union { unsigned short s[8]; uint4 u; } o;
    o.s[0] = f2bf(a.x); o.s[1] = f2bf(a.y); o.s[2] = f2bf(a.z); o.s[3] = f2bf(a.w);
    o.s[4] = f2bf(b.x); o.s[5] = f2bf(b.y); o.s[6] = f2bf(b.z); o.s[7] = f2bf(b.w);
    *(uint4*)(outp + (size_t)i * 8) = o.u;
}

// ---------------------------------------------------------------------------
// Pack concat weight [Wl;Wr]^T (B operand, [k=256][o=128]) into MFMA fragment
// order: frag[(ot*8+ks)*64 + lane][j] = B[ks*32 + (lane>>4)*8 + j][ot*16 + (lane&15)]
// ---------------------------------------------------------------------------
__global__ void k_wprep(const float* __restrict__ Wl, const float* __restrict__ Wr,
                        unsigned short* __restrict__ wbuf) {
    int tid = blockIdx.x * 256 + threadIdx.x;
    if (tid >= 8 * 8 * 64) return;
    int lane = tid & 63;
    int ks   = (tid >> 6) & 7;
    int ot   = tid >> 9;
    int o  = ot * 16 + (lane & 15);
    int kb = ks * 32 + ((lane >> 4) << 3);
    union { unsigned short s[8]; uint4 u; } frag;
    #pragma unroll
    for (int j = 0; j < 8; ++j) {
        int k = kb + j;
        float v = (k < DIM) ? Wl[o * DIM + k] : Wr[o * DIM + (k - DIM)];
        frag.s[j] = f2bf(v);
    }
    *(uint4*)(wbuf + (size_t)tid * 8) = frag.u;
}

// ---------------------------------------------------------------------------
// Pull-style mean-aggregation, MLP-optimized:
// 4 nodes per wave (quarter q = lane>>4 owns node, sub = lane&15 owns 16B of
// the 256B row). Edge loop unrolled 4x -> up to 16 outstanding row-gathers
// per wave. Stores mean directly in bf16 (invdeg folded in).
// ---------------------------------------------------------------------------
__global__ __launch_bounds__(256) void k_agg(const unsigned short* __restrict__ feat,
                                             const int* __restrict__ rs,
                                             const int* __restrict__ srcs,
                                             unsigned short* __restrict__ agg) {
    int gtid = blockIdx.x * 256 + threadIdx.x;
    int wid  = gtid >> 6;                 // wave id
    int lane = threadIdx.x & 63;
    int q    = lane >> 4;                 // quarter: which of 4 nodes
    int sub  = lane & 15;                 // 16B chunk within the row
    int node = wid * 4 + q;               // 12500 waves * 4 = 50000, exact
    int start = (node == 0) ? 0 : rs[node - 1];
    int end   = rs[node];

    float a0 = 0.f, a1 = 0.f, a2 = 0.f, a3 = 0.f;
    float a4 = 0.f, a5 = 0.f, a6 = 0.f, a7 = 0.f;
    const size_t coff = (size_t)sub * 8;

    int e = start;
    for (; e + 4 <= end; e += 4) {
        int s0 = srcs[e], s1 = srcs[e + 1], s2 = srcs[e + 2], s3 = srcs[e + 3];
        uint4 r0 = *(const uint4*)(feat + (size_t)s0 * DIM + coff);
        uint4 r1 = *(const uint4*)(feat + (size_t)s1 * DIM + coff);
        uint4 r2 = *(const uint4*)(feat + (size_t)s2 * DIM + coff);
        uint4 r3 = *(const uint4*)(feat + (size_t)s3 * DIM + coff);
        a0 += bflo(r0.x) + bflo(r1.x) + bflo(r2.x) + bflo(r3.x);
        a1 += bfhi(r0.x) + bfhi(r1.x) + bfhi(r2.x) + bfhi(r3.x);
        a2 += bflo(r0.y) + bflo(r1.y) + bflo(r2.y) + bflo(r3.y);
        a3 += bfhi(r0.y) + bfhi(r1.y) + bfhi(r2.y) + bfhi(r3.y);
        a4 += bflo(r0.z) + bflo(r1.z) + bflo(r2.z) + bflo(r3.z);
        a5 += bfhi(r0.z) + bfhi(r1.z) + bfhi(r2.z) + bfhi(r3.z);
        a6 += bflo(r0.w) + bflo(r1.w) + bflo(r2.w) + bflo(r3.w);
        a7 += bfhi(r0.w) + bfhi(r1.w) + bfhi(r2.w) + bfhi(r3.w);
    }
    for (; e < end; ++e) {
        uint4 r = *(const uint4*)(feat + (size_t)srcs[e] * DIM + coff);
        a0 += bflo(r.x); a1 += bfhi(r.x);
        a2 += bflo(r.y); a3 += bfhi(r.y);
        a4 += bflo(r.z); a5 += bfhi(r.z);
        a6 += bflo(r.w); a7 += bfhi(r.w);
    }

    float inv = 1.0f / fmaxf((float)(end - start), 1.0f);
    union { unsigned short s[8]; uint4 u; } o;
    o.s[0] = f2bf(a0 * inv); o.s[1] = f2bf(a1 * inv);
    o.s[2] = f2bf(a2 * inv); o.s[3] = f2bf(a3 * inv);
    o.s[4] = f2bf(a4 * inv); o.s[5] = f2bf(a5 * inv);
    o.s[6] = f2bf(a6 * inv); o.s[7] = f2bf(a7 * inv);
    *(uint4*)(agg + (size_t)node * DIM + coff) = o.u;
}

// ---------------------------------------------------------------------------
// Fused SAGE layer via MFMA: out = relu( [aggmean ; in2] @ Wcat + bias ), bf16.
// Block = 4 waves; wave w computes 16 nodes x 32 outs (out tiles 2w, 2w+1).
// ---------------------------------------------------------------------------
__global__ __launch_bounds__(256) void k_mm(const unsigned short* __restrict__ aggb,
                                            const unsigned short* __restrict__ in2b,
                                            const unsigned short* __restrict__ wbuf,
                                            const float* __restrict__ bias,
                                            unsigned short* __restrict__ outb) {
    int t    = threadIdx.x;
    int wave = t >> 6;
    int lane = t & 63;
    int n0   = blockIdx.x * 16;
    int row  = lane & 15;
    int kl   = (lane >> 4) << 3;

    bf16x8 B[2][8];
    #pragma unroll
    for (int ot = 0; ot < 2; ++ot)
        #pragma unroll
        for (int ks = 0; ks < 8; ++ks)
            B[ot][ks] = *(const bf16x8*)(wbuf +
                (((size_t)(wave * 2 + ot) * 8 + ks) * 64 + lane) * 8);

    bf16x8 A[8];
    const unsigned short* arow = aggb + (size_t)(n0 + row) * DIM + kl;
    const unsigned short* xrow = in2b + (size_t)(n0 + row) * DIM + kl;
    #pragma unroll
    for (int ks = 0; ks < 4; ++ks) A[ks]     = *(const bf16x8*)(arow + ks * 32);
    #pragma unroll
    for (int ks = 0; ks < 4; ++ks) A[4 + ks] = *(const bf16x8*)(xrow + ks * 32);

    f32x4 acc0 = {0.f, 0.f, 0.f, 0.f}, acc1 = {0.f, 0.f, 0.f, 0.f};
    #pragma unroll
    for (int ks = 0; ks < 8; ++ks) {
        acc0 = __builtin_amdgcn_mfma_f32_16x16x32_bf16(A[ks], B[0][ks], acc0, 0, 0, 0);
        acc1 = __builtin_amdgcn_mfma_f32_16x16x32_bf16(A[ks], B[1][ks], acc1, 0, 0, 0);
    }

    // C/D layout: col = lane&15, row = (lane>>4)*4 + reg   [m89-verified]
    int o0   = wave * 32;
    int ocol = lane & 15;
    int rb   = (lane >> 4) << 2;
    float b0 = bias[o0 + ocol];
    float b1 = bias[o0 + 16 + ocol];
    #pragma unroll
    for (int r = 0; r < 4; ++r) {
        size_t n = (size_t)(n0 + rb + r);
        outb[n * DIM + o0 + ocol]      = f2bf(fmaxf(acc0[r] + b0, 0.f));
        outb[n * DIM + o0 + 16 + ocol] = f2bf(fmaxf(acc1[r] + b1, 0.f));
    }
}

// ---------------------------------------------------------------------------
// Global mean pool (batch sorted -> binary search) + fused MLP head.
// ---------------------------------------------------------------------------
__global__ __launch_bounds__(256) void k_pool_head(const unsigned short* __restrict__ h2,
                                                   const int* __restrict__ batch,
                                                   const float* __restrict__ wl1,
                                                   const float* __restrict__ bl1,
                                                   const float* __restrict__ wout,
                                                   const float* __restrict__ bout,
                                                   float* __restrict__ out) {
    int g = blockIdx.x;
    int t = threadIdx.x;
    int lane = t & 63;
    int wv   = t >> 6;

    int lo = 0, hi = N_NODES;
    while (lo < hi) { int mid = (lo + hi) >> 1; if (batch[mid] < g) lo = mid + 1; else hi = mid; }
    int s = lo;
    lo = 0; hi = N_NODES;
    while (lo < hi) { int mid = (lo + hi) >> 1; if (batch[mid] < g + 1) lo = mid + 1; else hi = mid; }
    int e = lo;

    float ax = 0.f, ay = 0.f;
    for (int n = s + wv; n < e; n += 4) {
        unsigned u = *(const unsigned*)(h2 + (size_t)n * DIM + 2 * lane);
        ax += bflo(u); ay += bfhi(u);
    }
    __shared__ float red[4][DIM];
    __shared__ float gvec[DIM];
    red[wv][2 * lane] = ax; red[wv][2 * lane + 1] = ay;
    __syncthreads();
    if (t < DIM) {
        float sm = red[0][t] + red[1][t] + red[2][t] + red[3][t];
        float cnt = fmaxf((float)(e - s), 1.0f);
        gvec[t] = sm / cnt;
    }
    __syncthreads();
    if (t < 64) {
        float a = bl1[t];
        #pragma unroll 4
        for (int k = 0; k < DIM; ++k) a += wl1[t * DIM + k] * gvec[k];
        float g1 = fmaxf(a, 0.f) * wout[t];
        #pragma unroll
        for (int off = 32; off > 0; off >>= 1) g1 += __shfl_down(g1, off);
        if (t == 0) {
            float z = g1 + bout[0];
            out[g] = 1.0f / (1.0f + expf(-z));
        }
    }
}

// ---------------------------------------------------------------------------
extern "C" void kernel_launch(void* const* d_in, const int* in_sizes, int n_in,
                              void* d_out, int out_size, void* d_ws, size_t ws_size,
                              hipStream_t stream) {
    const float* x     = (const float*)d_in[0];
    const int*   ei    = (const int*)d_in[1];    // int64 in ref -> int32 here
    const int*   batch = (const int*)d_in[2];
    const float* w1l   = (const float*)d_in[3];
    const float* b1l   = (const float*)d_in[4];
    const float* w1r   = (const float*)d_in[5];
    const float* w2l   = (const float*)d_in[6];
    const float* b2l   = (const float*)d_in[7];
    const float* w2r   = (const float*)d_in[8];
    const float* wl1   = (const float*)d_in[9];
    const float* bl1   = (const float*)d_in[10];
    const float* wout  = (const float*)d_in[11];
    const float* bout  = (const float*)d_in[12];
    float* out = (float*)d_out;

    char*  wsp = (char*)d_ws;
    size_t off = 0;
    auto alloc = [&](size_t bytes) -> char* {
        char* p = wsp + off;
        off += (bytes + 255) & ~(size_t)255;
        return p;
    };
    int* rs   = (int*)alloc((size_t)(N_NODES + 1) * 4);
    int* hist = (int*)alloc((size_t)N_NODES * 4);
    int* bsum = (int*)alloc(256 * 4);
    int* srcs = (int*)alloc((size_t)N_EDGES * 4);
    unsigned short* xb    = (unsigned short*)alloc((size_t)N_NODES * DIM * 2);
    unsigned short* aggb  = (unsigned short*)alloc((size_t)N_NODES * DIM * 2);
    unsigned short* h1b   = (unsigned short*)alloc((size_t)N_NODES * DIM * 2);
    unsigned short* h2b   = (unsigned short*)alloc((size_t)N_NODES * DIM * 2);
    unsigned short* wbuf1 = (unsigned short*)alloc((size_t)8 * 8 * 64 * 8 * 2);
    unsigned short* wbuf2 = (unsigned short*)alloc((size_t)8 * 8 * 64 * 8 * 2);

    const int nb = (N_NODES + 511) / 512;   // 98

    hipMemsetAsync(hist, 0, (size_t)N_NODES * 4, stream);
    k_hist<<<(N_EDGES + 255) / 256, 256, 0, stream>>>(ei, hist);
    k_blocksum<<<nb, 256, 0, stream>>>(hist, bsum);
    k_scan_bsum<<<1, 64, 0, stream>>>(bsum, nb);
    k_scan_write<<<nb, 512, 0, stream>>>(hist, bsum, rs);
    k_place<<<(N_EDGES + 255) / 256, 256, 0, stream>>>(ei, rs, srcs);

    // dtype prep
    k_tobf16<<<(N_NODES * DIM / 8 + 255) / 256, 256, 0, stream>>>(x, xb, N_NODES * DIM / 8);
    k_wprep<<<16, 256, 0, stream>>>(w1l, w1r, wbuf1);
    k_wprep<<<16, 256, 0, stream>>>(w2l, w2r, wbuf2);

    // conv1 (16 nodes per block for k_agg: 4 waves x 4 nodes)
    k_agg<<<N_NODES / 16, 256, 0, stream>>>(xb, rs, srcs, aggb);
    k_mm<<<N_NODES / 16, 256, 0, stream>>>(aggb, xb, wbuf1, b1l, h1b);
    // conv2
    k_agg<<<N_NODES / 16, 256, 0, stream>>>(h1b, rs, srcs, aggb);
    k_mm<<<N_NODES / 16, 256, 0, stream>>>(aggb, h1b, wbuf2, b2l, h2b);
    // pool + head
    k_pool_head<<<N_GRAPHS, 256, 0, stream>>>(h2b, batch, wl1, bl1, wout, bout, out);
}

// Round 5
// 248.386 us; speedup vs baseline: 2.2247x; 1.1548x over previous
//
#include <hip/hip_runtime.h>
#include <cstdint>
#include <cstddef>

#define N_NODES  50000
#define N_EDGES  800000
#define DIM      128
#define N_GRAPHS 64

typedef __attribute__((ext_vector_type(8))) short     bf16x8;
typedef __attribute__((ext_vector_type(4))) float     f32x4;

__device__ __forceinline__ int clamp_node(int v) {
    return v < 0 ? 0 : (v >= N_NODES ? N_NODES - 1 : v);
}
__device__ __forceinline__ unsigned short f2bf(float f) {
    union { float f; unsigned u; } v; v.f = f;
    unsigned r = v.u + 0x7FFF + ((v.u >> 16) & 1);   // round-to-nearest-even
    return (unsigned short)(r >> 16);
}
__device__ __forceinline__ float bflo(unsigned u) {
    union { unsigned u; float f; } v; v.u = u << 16; return v.f;
}
__device__ __forceinline__ float bfhi(unsigned u) {
    union { unsigned u; float f; } v; v.u = u & 0xFFFF0000u; return v.f;
}

// ---------------------------------------------------------------------------
// CSR build: histogram of dst, scan, placement. edge_index arrives as int32.
// ---------------------------------------------------------------------------
__global__ void k_hist(const int* __restrict__ ei, int* __restrict__ hist) {
    int e = blockIdx.x * 256 + threadIdx.x;
    if (e < N_EDGES) atomicAdd(&hist[clamp_node(ei[N_EDGES + e])], 1);
}

__global__ void k_blocksum(const int* __restrict__ hist, int* __restrict__ bsum) {
    __shared__ int s[256];
    int base = blockIdx.x * 512;
    int t = threadIdx.x;
    int v = 0;
    if (base + t < N_NODES)       v += hist[base + t];
    if (base + 256 + t < N_NODES) v += hist[base + 256 + t];
    s[t] = v;
    __syncthreads();
    for (int off = 128; off > 0; off >>= 1) {
        if (t < off) s[t] += s[t + off];
        __syncthreads();
    }
    if (t == 0) bsum[blockIdx.x] = s[0];
}

__global__ void k_scan_bsum(int* bsum, int nb) {
    if (threadIdx.x == 0 && blockIdx.x == 0) {
        int acc = 0;
        for (int i = 0; i < nb; ++i) { int v = bsum[i]; bsum[i] = acc; acc += v; }
    }
}

__global__ void k_scan_write(const int* __restrict__ hist, const int* __restrict__ boff,
                             int* __restrict__ rs) {
    __shared__ int s[512];
    int t = threadIdx.x;
    int i = blockIdx.x * 512 + t;
    int v = (i < N_NODES) ? hist[i] : 0;
    s[t] = v;
    __syncthreads();
    for (int off = 1; off < 512; off <<= 1) {
        int y = (t >= off) ? s[t - off] : 0;
        __syncthreads();
        s[t] += y;
        __syncthreads();
    }
    int base = boff[blockIdx.x];
    if (i < N_NODES)      rs[i] = base + s[t] - v;
    if (i == N_NODES - 1) rs[N_NODES] = base + s[t];
}

// After this kernel rs[d] holds END offset of node d. start(n) = rs[n-1].
__global__ void k_place(const int* __restrict__ ei, int* __restrict__ rs,
                        int* __restrict__ srcs) {
    int e = blockIdx.x * 256 + threadIdx.x;
    if (e < N_EDGES) {
        int d = clamp_node(ei[N_EDGES + e]);
        int pos = atomicAdd(&rs[d], 1);
        if (pos >= 0 && pos < N_EDGES) srcs[pos] = clamp_node(ei[e]);
    }
}

// ---------------------------------------------------------------------------
// f32 -> bf16 bulk convert (8 elems/thread).
// ---------------------------------------------------------------------------
__global__ __launch_bounds__(256) void k_tobf16(const float* __restrict__ in,
                                                unsigned short* __restrict__ outp,
                                                int n8) {
    int i = blockIdx.x * 256 + threadIdx.x;
    if (i >= n8) return;
    const float4* p = (const float4*)(in + (size_t)i * 8);
    float4 a = p[0], b = p[1];
    union { unsigned short s[8]; uint4 u; } o;
    o.s[0] = f2bf(a.x); o.s[1] = f2bf(a.y); o.s[2] = f2bf(a.z); o.s[3] = f2bf(a.w);
    o.s[4] = f2bf(b.x); o.s[5] = f2bf(b.y); o.s[6] = f2bf(b.z); o.s[7] = f2bf(b.w);
    *(uint4*)(outp + (size_t)i * 8) = o.u;
}

// ---------------------------------------------------------------------------
// Pack concat weight [Wl;Wr]^T (B operand, [k=256][o=128]) into MFMA fragment
// order: frag[(ot*8+ks)*64 + lane][j] = B[ks*32 + (lane>>4)*8 + j][ot*16 + (lane&15)]
// ---------------------------------------------------------------------------
__global__ void k_wprep(const float* __restrict__ Wl, const float* __restrict__ Wr,
                        unsigned short* __restrict__ wbuf) {
    int tid = blockIdx.x * 256 + threadIdx.x;
    if (tid >= 8 * 8 * 64) return;
    int lane = tid & 63;
    int ks   = (tid >> 6) & 7;
    int ot   = tid >> 9;
    int o  = ot * 16 + (lane & 15);
    int kb = ks * 32 + ((lane >> 4) << 3);
    union { unsigned short s[8]; uint4 u; } frag;
    #pragma unroll
    for (int j = 0; j < 8; ++j) {
        int k = kb + j;
        float v = (k < DIM) ? Wl[o * DIM + k] : Wr[o * DIM + (k - DIM)];
        frag.s[j] = f2bf(v);
    }
    *(uint4*)(wbuf + (size_t)tid * 8) = frag.u;
}

// ---------------------------------------------------------------------------
// Pull-style mean-aggregation: 4 nodes per wave, 4x unrolled edge loop.
// ---------------------------------------------------------------------------
__global__ __launch_bounds__(256) void k_agg(const unsigned short* __restrict__ feat,
                                             const int* __restrict__ rs,
                                             const int* __restrict__ srcs,
                                             unsigned short* __restrict__ agg) {
    int gtid = blockIdx.x * 256 + threadIdx.x;
    int wid  = gtid >> 6;                 // wave id
    int lane = threadIdx.x & 63;
    int q    = lane >> 4;                 // quarter: which of 4 nodes
    int sub  = lane & 15;                 // 16B chunk within the row
    int node = wid * 4 + q;               // 12500 waves * 4 = 50000, exact
    int start = (node == 0) ? 0 : rs[node - 1];
    int end   = rs[node];

    float a0 = 0.f, a1 = 0.f, a2 = 0.f, a3 = 0.f;
    float a4 = 0.f, a5 = 0.f, a6 = 0.f, a7 = 0.f;
    const size_t coff = (size_t)sub * 8;

    int e = start;
    for (; e + 4 <= end; e += 4) {
        int s0 = srcs[e], s1 = srcs[e + 1], s2 = srcs[e + 2], s3 = srcs[e + 3];
        uint4 r0 = *(const uint4*)(feat + (size_t)s0 * DIM + coff);
        uint4 r1 = *(const uint4*)(feat + (size_t)s1 * DIM + coff);
        uint4 r2 = *(const uint4*)(feat + (size_t)s2 * DIM + coff);
        uint4 r3 = *(const uint4*)(feat + (size_t)s3 * DIM + coff);
        a0 += bflo(r0.x) + bflo(r1.x) + bflo(r2.x) + bflo(r3.x);
        a1 += bfhi(r0.x) + bfhi(r1.x) + bfhi(r2.x) + bfhi(r3.x);
        a2 += bflo(r0.y) + bflo(r1.y) + bflo(r2.y) + bflo(r3.y);
        a3 += bfhi(r0.y) + bfhi(r1.y) + bfhi(r2.y) + bfhi(r3.y);
        a4 += bflo(r0.z) + bflo(r1.z) + bflo(r2.z) + bflo(r3.z);
        a5 += bfhi(r0.z) + bfhi(r1.z) + bfhi(r2.z) + bfhi(r3.z);
        a6 += bflo(r0.w) + bflo(r1.w) + bflo(r2.w) + bflo(r3.w);
        a7 += bfhi(r0.w) + bfhi(r1.w) + bfhi(r2.w) + bfhi(r3.w);
    }
    for (; e < end; ++e) {
        uint4 r = *(const uint4*)(feat + (size_t)srcs[e] * DIM + coff);
        a0 += bflo(r.x); a1 += bfhi(r.x);
        a2 += bflo(r.y); a3 += bfhi(r.y);
        a4 += bflo(r.z); a5 += bfhi(r.z);
        a6 += bflo(r.w); a7 += bfhi(r.w);
    }

    float inv = 1.0f / fmaxf((float)(end - start), 1.0f);
    union { unsigned short s[8]; uint4 u; } o;
    o.s[0] = f2bf(a0 * inv); o.s[1] = f2bf(a1 * inv);
    o.s[2] = f2bf(a2 * inv); o.s[3] = f2bf(a3 * inv);
    o.s[4] = f2bf(a4 * inv); o.s[5] = f2bf(a5 * inv);
    o.s[6] = f2bf(a6 * inv); o.s[7] = f2bf(a7 * inv);
    *(uint4*)(agg + (size_t)node * DIM + coff) = o.u;
}

// ---------------------------------------------------------------------------
// Fused SAGE layer via MFMA: out = relu( [aggmean ; in2] @ Wcat + bias ), bf16.
// Block = 4 waves; wave w computes 16 nodes x 32 outs (out tiles 2w, 2w+1).
// ---------------------------------------------------------------------------
__global__ __launch_bounds__(256) void k_mm(const unsigned short* __restrict__ aggb,
                                            const unsigned short* __restrict__ in2b,
                                            const unsigned short* __restrict__ wbuf,
                                            const float* __restrict__ bias,
                                            unsigned short* __restrict__ outb) {
    int t    = threadIdx.x;
    int wave = t >> 6;
    int lane = t & 63;
    int n0   = blockIdx.x * 16;
    int row  = lane & 15;
    int kl   = (lane >> 4) << 3;

    bf16x8 B[2][8];
    #pragma unroll
    for (int ot = 0; ot < 2; ++ot)
        #pragma unroll
        for (int ks = 0; ks < 8; ++ks)
            B[ot][ks] = *(const bf16x8*)(wbuf +
                (((size_t)(wave * 2 + ot) * 8 + ks) * 64 + lane) * 8);

    bf16x8 A[8];
    const unsigned short* arow = aggb + (size_t)(n0 + row) * DIM + kl;
    const unsigned short* xrow = in2b + (size_t)(n0 + row) * DIM + kl;
    #pragma unroll
    for (int ks = 0; ks < 4; ++ks) A[ks]     = *(const bf16x8*)(arow + ks * 32);
    #pragma unroll
    for (int ks = 0; ks < 4; ++ks) A[4 + ks] = *(const bf16x8*)(xrow + ks * 32);

    f32x4 acc0 = {0.f, 0.f, 0.f, 0.f}, acc1 = {0.f, 0.f, 0.f, 0.f};
    #pragma unroll
    for (int ks = 0; ks < 8; ++ks) {
        acc0 = __builtin_amdgcn_mfma_f32_16x16x32_bf16(A[ks], B[0][ks], acc0, 0, 0, 0);
        acc1 = __builtin_amdgcn_mfma_f32_16x16x32_bf16(A[ks], B[1][ks], acc1, 0, 0, 0);
    }

    // C/D layout: col = lane&15, row = (lane>>4)*4 + reg   [m89-verified]
    int o0   = wave * 32;
    int ocol = lane & 15;
    int rb   = (lane >> 4) << 2;
    float b0 = bias[o0 + ocol];
    float b1 = bias[o0 + 16 + ocol];
    #pragma unroll
    for (int r = 0; r < 4; ++r) {
        size_t n = (size_t)(n0 + rb + r);
        outb[n * DIM + o0 + ocol]      = f2bf(fmaxf(acc0[r] + b0, 0.f));
        outb[n * DIM + o0 + 16 + ocol] = f2bf(fmaxf(acc1[r] + b1, 0.f));
    }
}

// ---------------------------------------------------------------------------
// Pool stage 1: partial per-graph sums. Block = 4 waves; wave owns 32
// contiguous nodes, lane owns 2 dims. batch sorted -> register accumulate,
// flush to gsum atomics only on graph change (~2 flushes/wave).
// ---------------------------------------------------------------------------
__global__ __launch_bounds__(256) void k_pool_partial(const unsigned short* __restrict__ h2,
                                                      const int* __restrict__ batch,
                                                      float* __restrict__ gsum) {
    int wid  = (blockIdx.x * 256 + threadIdx.x) >> 6;
    int lane = threadIdx.x & 63;
    int n0 = wid * 32;
    if (n0 >= N_NODES) return;
    int n1 = n0 + 32; if (n1 > N_NODES) n1 = N_NODES;
    int col = lane * 2;

    float ax = 0.f, ay = 0.f;
    int cur = batch[n0];
    for (int n = n0; n < n1; ++n) {
        int b = batch[n];
        if (b != cur) {
            atomicAdd(&gsum[cur * DIM + col], ax);
            atomicAdd(&gsum[cur * DIM + col + 1], ay);
            ax = 0.f; ay = 0.f; cur = b;
        }
        unsigned u = *(const unsigned*)(h2 + (size_t)n * DIM + col);
        ax += bflo(u); ay += bfhi(u);
    }
    atomicAdd(&gsum[cur * DIM + col], ax);
    atomicAdd(&gsum[cur * DIM + col + 1], ay);
}

// ---------------------------------------------------------------------------
// Pool stage 2: mean (count via binary search on sorted batch) + MLP head.
// One block per graph.
// ---------------------------------------------------------------------------
__global__ __launch_bounds__(256) void k_head(const float* __restrict__ gsum,
                                              const int* __restrict__ batch,
                                              const float* __restrict__ wl1,
                                              const float* __restrict__ bl1,
                                              const float* __restrict__ wout,
                                              const float* __restrict__ bout,
                                              float* __restrict__ out) {
    int g = blockIdx.x;
    int t = threadIdx.x;

    int lo = 0, hi = N_NODES;
    while (lo < hi) { int mid = (lo + hi) >> 1; if (batch[mid] < g) lo = mid + 1; else hi = mid; }
    int s = lo;
    lo = 0; hi = N_NODES;
    while (lo < hi) { int mid = (lo + hi) >> 1; if (batch[mid] < g + 1) lo = mid + 1; else hi = mid; }
    int e = lo;

    __shared__ float gvec[DIM];
    if (t < DIM) {
        float cnt = fmaxf((float)(e - s), 1.0f);
        gvec[t] = gsum[g * DIM + t] / cnt;
    }
    __syncthreads();
    if (t < 64) {
        float a = bl1[t];
        #pragma unroll 4
        for (int k = 0; k < DIM; ++k) a += wl1[t * DIM + k] * gvec[k];
        float g1 = fmaxf(a, 0.f) * wout[t];
        #pragma unroll
        for (int off = 32; off > 0; off >>= 1) g1 += __shfl_down(g1, off);
        if (t == 0) {
            float z = g1 + bout[0];
            out[g] = 1.0f / (1.0f + expf(-z));
        }
    }
}

// ---------------------------------------------------------------------------
extern "C" void kernel_launch(void* const* d_in, const int* in_sizes, int n_in,
                              void* d_out, int out_size, void* d_ws, size_t ws_size,
                              hipStream_t stream) {
    const float* x     = (const float*)d_in[0];
    const int*   ei    = (const int*)d_in[1];    // int64 in ref -> int32 here
    const int*   batch = (const int*)d_in[2];
    const float* w1l   = (const float*)d_in[3];
    const float* b1l   = (const float*)d_in[4];
    const float* w1r   = (const float*)d_in[5];
    const float* w2l   = (const float*)d_in[6];
    const float* b2l   = (const float*)d_in[7];
    const float* w2r   = (const float*)d_in[8];
    const float* wl1   = (const float*)d_in[9];
    const float* bl1   = (const float*)d_in[10];
    const float* wout  = (const float*)d_in[11];
    const float* bout  = (const float*)d_in[12];
    float* out = (float*)d_out;

    char*  wsp = (char*)d_ws;
    size_t off = 0;
    auto alloc = [&](size_t bytes) -> char* {
        char* p = wsp + off;
        off += (bytes + 255) & ~(size_t)255;
        return p;
    };
    int* rs   = (int*)alloc((size_t)(N_NODES + 1) * 4);
    int* hist = (int*)alloc((size_t)N_NODES * 4);
    int* bsum = (int*)alloc(256 * 4);
    int* srcs = (int*)alloc((size_t)N_EDGES * 4);
    unsigned short* xb    = (unsigned short*)alloc((size_t)N_NODES * DIM * 2);
    unsigned short* aggb  = (unsigned short*)alloc((size_t)N_NODES * DIM * 2);
    unsigned short* h1b   = (unsigned short*)alloc((size_t)N_NODES * DIM * 2);
    unsigned short* h2b   = (unsigned short*)alloc((size_t)N_NODES * DIM * 2);
    unsigned short* wbuf1 = (unsigned short*)alloc((size_t)8 * 8 * 64 * 8 * 2);
    unsigned short* wbuf2 = (unsigned short*)alloc((size_t)8 * 8 * 64 * 8 * 2);
    float* gsum = (float*)alloc((size_t)N_GRAPHS * DIM * 4);

    const int nb = (N_NODES + 511) / 512;   // 98

    hipMemsetAsync(hist, 0, (size_t)N_NODES * 4, stream);
    hipMemsetAsync(gsum, 0, (size_t)N_GRAPHS * DIM * 4, stream);
    k_hist<<<(N_EDGES + 255) / 256, 256, 0, stream>>>(ei, hist);
    k_blocksum<<<nb, 256, 0, stream>>>(hist, bsum);
    k_scan_bsum<<<1, 64, 0, stream>>>(bsum, nb);
    k_scan_write<<<nb, 512, 0, stream>>>(hist, bsum, rs);
    k_place<<<(N_EDGES + 255) / 256, 256, 0, stream>>>(ei, rs, srcs);

    // dtype prep
    k_tobf16<<<(N_NODES * DIM / 8 + 255) / 256, 256, 0, stream>>>(x, xb, N_NODES * DIM / 8);
    k_wprep<<<16, 256, 0, stream>>>(w1l, w1r, wbuf1);
    k_wprep<<<16, 256, 0, stream>>>(w2l, w2r, wbuf2);

    // conv1
    k_agg<<<N_NODES / 16, 256, 0, stream>>>(xb, rs, srcs, aggb);
    k_mm<<<N_NODES / 16, 256, 0, stream>>>(aggb, xb, wbuf1, b1l, h1b);
    // conv2
    k_agg<<<N_NODES / 16, 256, 0, stream>>>(h1b, rs, srcs, aggb);
    k_mm<<<N_NODES / 16, 256, 0, stream>>>(aggb, h1b, wbuf2, b2l, h2b);
    // pool (2-stage) + head
    k_pool_partial<<<(N_NODES + 127) / 128, 256, 0, stream>>>(h2b, batch, gsum);
    k_head<<<N_GRAPHS, 256, 0, stream>>>(gsum, batch, wl1, bl1, wout, bout, out);
}